// Round 21
// baseline (1101.934 us; speedup 1.0000x reference)
//
#include <hip/hip_runtime.h>

typedef unsigned short u16;
typedef __attribute__((ext_vector_type(8))) short bf16x8;
typedef __attribute__((ext_vector_type(4))) float f32x4;

// ---- bf16 helpers (RNE) ----
__device__ inline float bf2f(u16 u) {
    unsigned v = ((unsigned)u) << 16;
    return __builtin_bit_cast(float, v);
}
__device__ inline u16 f2bf(float f) {
    unsigned u = __builtin_bit_cast(unsigned, f);
    u += 0x7fff + ((u >> 16) & 1);
    return (u16)(u >> 16);
}

// ---- async global->LDS 16B (wave-uniform LDS base + lane*16; per-lane gsrc)
__device__ inline void load_lds16(const u16* g, u16* l) {
    __builtin_amdgcn_global_load_lds(
        (const __attribute__((address_space(1))) unsigned int*)g,
        (__attribute__((address_space(3))) unsigned int*)l, 16, 0, 0);
}

// ============================================================
// Dtype detector (fp32 vs bf16 device buffers). flag=1 -> fp32.
// ============================================================
__global__ void detect_kernel(const u16* __restrict__ xr, int* __restrict__ flag) {
    __shared__ int red[4];
    const int t = threadIdx.x;
    int cnt = 0;
    for (int j = 0; j < 64; ++j) {
        u16 v = xr[(t * 64 + j) * 2];
        int e = (v >> 7) & 0xFF;
        cnt += (e >= 0x86);
    }
    for (int o = 32; o >= 1; o >>= 1) cnt += __shfl_xor(cnt, o);
    if ((t & 63) == 0) red[t >> 6] = cnt;
    __syncthreads();
    if (t == 0) flag[0] = ((red[0] + red[1] + red[2] + red[3]) > 1000) ? 1 : 0;
}

// ============================================================
// Convert x (fp32 or bf16) -> xbf (bf16), 8 elems/thread, one pass.
// ============================================================
__global__ __launch_bounds__(256) void convert_kernel(const float* __restrict__ xf,
                                                      const u16* __restrict__ xh,
                                                      u16* __restrict__ xbf,
                                                      const int* __restrict__ flag) {
    const bool isf32 = flag[0] != 0;
    size_t i = ((size_t)blockIdx.x * 256 + threadIdx.x) * 8;
    if (isf32) {
        f32x4 f0 = *(const f32x4*)&xf[i];
        f32x4 f1 = *(const f32x4*)&xf[i + 4];
        bf16x8 v;
#pragma unroll
        for (int j = 0; j < 4; ++j) {
            v[j] = (short)f2bf(f0[j]);
            v[j + 4] = (short)f2bf(f1[j]);
        }
        *(bf16x8*)&xbf[i] = v;
    } else {
        *(bf16x8*)&xbf[i] = *(const bf16x8*)&xh[i];
    }
}

// ============================================================
// Weight transpose + convert-to-bf16: dst[C][R] = bf16(src[R][C])
// ============================================================
__global__ __launch_bounds__(256) void transpose_kernel(const float* __restrict__ srcf,
                                                        const u16* __restrict__ srch,
                                                        u16* __restrict__ dst,
                                                        int R, int C,
                                                        const int* __restrict__ flag) {
    __shared__ u16 tile[64][65];
    const bool isf32 = flag[0] != 0;
    const int t = threadIdx.x;
    const int c0 = blockIdx.x * 64, r0 = blockIdx.y * 64;
    const int lc = t & 63, lr4 = t >> 6;
#pragma unroll
    for (int i = 0; i < 16; ++i) {
        int row = i * 4 + lr4;
        size_t idx = (size_t)(r0 + row) * C + c0 + lc;
        tile[row][lc] = isf32 ? f2bf(srcf[idx]) : srch[idx];
    }
    __syncthreads();
#pragma unroll
    for (int i = 0; i < 16; ++i) {
        int drow = i * 4 + lr4;
        dst[(size_t)(c0 + drow) * R + r0 + lc] = tile[lc][drow];
    }
}

// ============================================================
// GEMM1: proj[65536][1024] = xbf[65536][512] @ W1 + bias1, bf16 out
// global_load_lds width=16 staging + XCD-chunked 1D grid (r19/r20-proven).
// ============================================================
__global__ __launch_bounds__(256) void gemm1_kernel(const u16* __restrict__ xbf,
                                                    const u16* __restrict__ w1t,
                                                    const float* __restrict__ b1f,
                                                    const u16* __restrict__ b1h,
                                                    u16* __restrict__ proj,
                                                    const int* __restrict__ flag) {
    __shared__ u16 Al[128 * 64];
    __shared__ u16 Bl[128 * 64];
    const bool isf32 = flag[0] != 0;
    const int t = threadIdx.x;
    const int lane = t & 63;
    const int w = t >> 6;
    const int i_wg = blockIdx.x;
    const int xcd = i_wg & 7;
    const int j = i_wg >> 3;
    const int r0 = (xcd * 64 + (j >> 3)) * 128;
    const int c0 = (j & 7) * 128;
    const int wr = (w >> 1) * 64, wc = (w & 1) * 64;

    f32x4 acc[4][4] = {};

    for (int kt = 0; kt < 8; ++kt) {
        const int k0 = kt * 64;
#pragma unroll
        for (int i = 0; i < 4; ++i) {
            int c = i * 256 + t;
            int row = c >> 3;
            int off = (c & 7) * 8;
            load_lds16(&xbf[(size_t)(r0 + row) * 512 + k0 + off], &Al[row * 64 + off]);
            load_lds16(&w1t[(size_t)(c0 + row) * 512 + k0 + off], &Bl[row * 64 + off]);
        }
        __syncthreads();
#pragma unroll
        for (int kk = 0; kk < 64; kk += 32) {
            bf16x8 a[4], bb[4];
#pragma unroll
            for (int m = 0; m < 4; ++m)
                a[m] = *(const bf16x8*)&Al[(wr + m * 16 + (lane & 15)) * 64 + kk + (lane >> 4) * 8];
#pragma unroll
            for (int n = 0; n < 4; ++n)
                bb[n] = *(const bf16x8*)&Bl[(wc + n * 16 + (lane & 15)) * 64 + kk + (lane >> 4) * 8];
#pragma unroll
            for (int m = 0; m < 4; ++m)
#pragma unroll
                for (int n = 0; n < 4; ++n)
                    acc[m][n] = __builtin_amdgcn_mfma_f32_16x16x32_bf16(a[m], bb[n], acc[m][n], 0, 0, 0);
        }
        __syncthreads();
    }

#pragma unroll
    for (int n = 0; n < 4; ++n) {
        int col = c0 + wc + n * 16 + (lane & 15);
        float bv = isf32 ? b1f[col] : bf2f(b1h[col]);
#pragma unroll
        for (int m = 0; m < 4; ++m) {
            int rbase = r0 + wr + m * 16 + (lane >> 4) * 4;
#pragma unroll
            for (int i = 0; i < 4; ++i)
                proj[(size_t)(rbase + i) * 1024 + col] = f2bf(acc[m][n][i] + bv);
        }
    }
}

// ============================================================
// Attention core per wg = (batch b, 64 query rows)  -- QBLK=64.
// r14/r18/r19/r20 structure FROZEN; single probe this round: T5 s_setprio
// around the QK and PV MFMA clusters (scheduler hint, no correctness
// surface). Mechanism: 2 waves/SIMD with interleaved gather/MFMA phases --
// priority lets the MFMA-ready wave preempt its gather-issuing SIMD-mate.
// ============================================================
__global__ __launch_bounds__(512, 2) void attn_kernel(const u16* __restrict__ proj,
                                                      u16* __restrict__ obuf) {
    __shared__ u16 Pl[64 * 512];            // 65536 B exactly
    const int t = threadIdx.x;
    const int lane = t & 63;
    const int w = t >> 6;                   // 0..7
    const int i_wg = blockIdx.x;
    const int xcd = i_wg & 7;
    const int q = (i_wg >> 3) & 15;
    const int b = (i_wg >> 7) * 8 + xcd;
    const int n0 = q * 64;
    const u16* pb = proj + (size_t)b * 1024 * 1024;
    const int g = lane >> 4;
    const int lr = lane & 15;

    // ---- Phase 1: S = Q @ relu(K)^T / 32, full 64x1024 in regs (4rf x 8cf)
    f32x4 acc[4][8] = {};
    const int mw = w * 128;
    for (int kk = 0; kk < 1024; kk += 32) {
        const int e = kk + g * 8;
        bf16x8 a[4];
#pragma unroll
        for (int rf = 0; rf < 4; ++rf)
            a[rf] = *(const bf16x8*)&pb[(size_t)(n0 + rf * 16 + lr) * 1024 + e];
#pragma unroll
        for (int c2 = 0; c2 < 2; ++c2) {     // kf in 2 chunks of 4 (reg relief)
            bf16x8 kf[4];
#pragma unroll
            for (int cf = 0; cf < 4; ++cf) {
                bf16x8 v = *(const bf16x8*)&pb[(size_t)(mw + c2 * 64 + cf * 16 + lr) * 1024 + e];
                v &= ~(v >> 15);   // bf16 relu
                kf[cf] = v;
            }
            __builtin_amdgcn_s_setprio(1);
#pragma unroll
            for (int rf = 0; rf < 4; ++rf)
#pragma unroll
                for (int cf = 0; cf < 4; ++cf)
                    acc[rf][c2 * 4 + cf] =
                        __builtin_amdgcn_mfma_f32_16x16x32_bf16(a[rf], kf[cf], acc[rf][c2 * 4 + cf], 0, 0, 0);
            __builtin_amdgcn_s_setprio(0);
        }
    }
    {
        const float sc = 1.0f / 32.0f;
#pragma unroll
        for (int rf = 0; rf < 4; ++rf)
#pragma unroll
            for (int cf = 0; cf < 8; ++cf)
#pragma unroll
                for (int i = 0; i < 4; ++i) acc[rf][cf][i] *= sc;
    }

    // ---- Phase 2: softmax. Row ri = rf*16 + g*4 + i; wave holds 8 cf x 16 lr.
    float* redm = (float*)Pl;          // [64][8] f32 (2 KiB) overlay
    float* reds = (float*)Pl + 512;    // [64][8] f32 (2 KiB) overlay
    {
#pragma unroll
        for (int rf = 0; rf < 4; ++rf)
#pragma unroll
            for (int i = 0; i < 4; ++i) {
                float m = acc[rf][0][i];
#pragma unroll
                for (int cf = 1; cf < 8; ++cf) m = fmaxf(m, acc[rf][cf][i]);
                for (int o = 8; o >= 1; o >>= 1) m = fmaxf(m, __shfl_xor(m, o));
                if (lr == 0) redm[(rf * 16 + g * 4 + i) * 8 + w] = m;
            }
    }
    __syncthreads();
    {
#pragma unroll
        for (int rf = 0; rf < 4; ++rf)
#pragma unroll
            for (int i = 0; i < 4; ++i) {
                int ri = rf * 16 + g * 4 + i;
                float m = redm[ri * 8 + 0];
#pragma unroll
                for (int w2 = 1; w2 < 8; ++w2) m = fmaxf(m, redm[ri * 8 + w2]);
                float s = 0.f;
#pragma unroll
                for (int cf = 0; cf < 8; ++cf) {
                    acc[rf][cf][i] = __expf(acc[rf][cf][i] - m);
                    s += acc[rf][cf][i];
                }
                for (int o = 8; o >= 1; o >>= 1) s += __shfl_xor(s, o);
                if (lr == 0) reds[ri * 8 + w] = s;
            }
    }
    __syncthreads();
    {
#pragma unroll
        for (int rf = 0; rf < 4; ++rf)
#pragma unroll
            for (int i = 0; i < 4; ++i) {
                int ri = rf * 16 + g * 4 + i;
                float s = reds[ri * 8 + 0];
#pragma unroll
                for (int w2 = 1; w2 < 8; ++w2) s += reds[ri * 8 + w2];
                float inv = 1.0f / s;
#pragma unroll
                for (int cf = 0; cf < 8; ++cf) acc[rf][cf][i] *= inv;
            }
    }
    __syncthreads();   // reduce overlay consumed -> P may overwrite

    // ---- Phase 3: O = P @ V ; es = e-set (512 cols), h = key-half.
    const int ew = w * 64;
#pragma unroll
    for (int es = 0; es < 2; ++es) {
        f32x4 acc2[4][4] = {};
#pragma unroll
        for (int h = 0; h < 2; ++h) {
            // waves owning key-half h write P-half [64][512] from live acc
            if ((w >> 2) == h) {
                char* Pb = (char*)Pl;
                const int cb = (w & 3) * 128;   // local key-col base
#pragma unroll
                for (int rf = 0; rf < 4; ++rf)
#pragma unroll
                    for (int i = 0; i < 4; ++i) {
                        int ri = rf * 16 + g * 4 + i;
                        int rx = (ri & 7) << 4;
                        char* prow = Pb + ri * 1024;
#pragma unroll
                        for (int cf = 0; cf < 8; ++cf) {
                            int c = cb + cf * 16 + lr;
                            *(u16*)(prow + ((2 * c) ^ rx)) = f2bf(acc[rf][cf][i]);
                        }
                    }
            }
            __syncthreads();
            // PV over keys [512h, 512h+512), wave's 64 e-cols in e-set es
            const char* Pb = (const char*)Pl;
            for (int m0 = 0; m0 < 512; m0 += 32) {
                const int mq = m0 + g * 8;
                bf16x8 pa[4];
#pragma unroll
                for (int rf = 0; rf < 4; ++rf) {
                    int pr = rf * 16 + lr;
                    pa[rf] = *(const bf16x8*)(Pb + pr * 1024 + ((2 * mq) ^ ((pr & 7) << 4)));
                }
#pragma unroll
                for (int cf = 0; cf < 4; ++cf) {
                    const u16* vp = &pb[(size_t)(h * 512 + mq) * 1024 + es * 512 + ew + cf * 16 + lr];
                    bf16x8 vv;
#pragma unroll
                    for (int j = 0; j < 8; ++j) vv[j] = (short)vp[(size_t)j * 1024];
                    __builtin_amdgcn_s_setprio(1);
#pragma unroll
                    for (int rf = 0; rf < 4; ++rf)
                        acc2[rf][cf] = __builtin_amdgcn_mfma_f32_16x16x32_bf16(pa[rf], vv, acc2[rf][cf], 0, 0, 0);
                    __builtin_amdgcn_s_setprio(0);
                }
            }
            __syncthreads();   // PV done before next P-half overwrite
        }
        // obuf write for this e-set
#pragma unroll
        for (int rf = 0; rf < 4; ++rf)
#pragma unroll
            for (int cf = 0; cf < 4; ++cf)
#pragma unroll
                for (int i = 0; i < 4; ++i)
                    obuf[((size_t)b * 1024 + n0 + rf * 16 + g * 4 + i) * 1024 +
                         es * 512 + ew + cf * 16 + lr] = f2bf(acc2[rf][cf][i]);
    }
}

// ============================================================
// GEMM2: out[65536][512] = relu(O[65536][1024] @ W2 + bias2)
// global_load_lds staging + XCD-chunked 1D grid (r19/r20-proven).
// ============================================================
__global__ __launch_bounds__(256) void gemm2_kernel(const u16* __restrict__ obuf,
                                                    const u16* __restrict__ w2t,
                                                    const float* __restrict__ b2f,
                                                    const u16* __restrict__ b2h,
                                                    float* __restrict__ outf,
                                                    u16* __restrict__ outh,
                                                    const int* __restrict__ flag) {
    __shared__ u16 Al[128 * 64];
    __shared__ u16 Bl[128 * 64];
    const bool isf32 = flag[0] != 0;
    const int t = threadIdx.x;
    const int lane = t & 63;
    const int w = t >> 6;
    const int i_wg = blockIdx.x;
    const int xcd = i_wg & 7;
    const int j = i_wg >> 3;
    const int r0 = (xcd * 64 + (j >> 2)) * 128;
    const int c0 = (j & 3) * 128;
    const int wr = (w >> 1) * 64, wc = (w & 1) * 64;

    f32x4 acc[4][4] = {};

    for (int kt = 0; kt < 16; ++kt) {
        const int k0 = kt * 64;
#pragma unroll
        for (int i = 0; i < 4; ++i) {
            int c = i * 256 + t;
            int row = c >> 3;
            int off = (c & 7) * 8;
            load_lds16(&obuf[(size_t)(r0 + row) * 1024 + k0 + off], &Al[row * 64 + off]);
            load_lds16(&w2t[(size_t)(c0 + row) * 1024 + k0 + off], &Bl[row * 64 + off]);
        }
        __syncthreads();
#pragma unroll
        for (int kk = 0; kk < 64; kk += 32) {
            bf16x8 a[4], bb[4];
#pragma unroll
            for (int m = 0; m < 4; ++m)
                a[m] = *(const bf16x8*)&Al[(wr + m * 16 + (lane & 15)) * 64 + kk + (lane >> 4) * 8];
#pragma unroll
            for (int n = 0; n < 4; ++n)
                bb[n] = *(const bf16x8*)&Bl[(wc + n * 16 + (lane & 15)) * 64 + kk + (lane >> 4) * 8];
#pragma unroll
            for (int m = 0; m < 4; ++m)
#pragma unroll
                for (int n = 0; n < 4; ++n)
                    acc[m][n] = __builtin_amdgcn_mfma_f32_16x16x32_bf16(a[m], bb[n], acc[m][n], 0, 0, 0);
        }
        __syncthreads();
    }

#pragma unroll
    for (int n = 0; n < 4; ++n) {
        int col = c0 + wc + n * 16 + (lane & 15);
        float bv = isf32 ? b2f[col] : bf2f(b2h[col]);
#pragma unroll
        for (int m = 0; m < 4; ++m) {
            int rbase = r0 + wr + m * 16 + (lane >> 4) * 4;
#pragma unroll
            for (int i = 0; i < 4; ++i) {
                float v = fmaxf(acc[m][n][i] + bv, 0.f);
                size_t oi = (size_t)(rbase + i) * 512 + col;
                if (isf32) outf[oi] = v;
                else outh[oi] = f2bf(v);
            }
        }
    }
}

// ============================================================
// Launch. ws: [0,1MB) W1T | [1MB,2MB) W2T | [2MB,130MB) proj | flag @130MB
//         | obuf [65536][1024] bf16 @130MB+4KB
// xbf (64MB) ALIASES the start of obuf (dead before attn writes obuf).
// ============================================================
extern "C" void kernel_launch(void* const* d_in, const int* in_sizes, int n_in,
                              void* d_out, int out_size, void* d_ws, size_t ws_size,
                              hipStream_t stream) {
    char* ws = (char*)d_ws;
    u16* W1T  = (u16*)ws;
    u16* W2T  = (u16*)(ws + (1u << 20));
    u16* proj = (u16*)(ws + (2u << 20));
    int* flag = (int*)(ws + ((size_t)130 << 20));
    u16* obuf = (u16*)(ws + ((size_t)130 << 20) + 4096);
    u16* xbf  = obuf;   // alias: dead before attn writes obuf

    detect_kernel<<<1, 256, 0, stream>>>((const u16*)d_in[0], flag);

    transpose_kernel<<<dim3(16, 8, 1), 256, 0, stream>>>(
        (const float*)d_in[1], (const u16*)d_in[1], W1T, 512, 1024, flag);
    transpose_kernel<<<dim3(8, 16, 1), 256, 0, stream>>>(
        (const float*)d_in[3], (const u16*)d_in[3], W2T, 1024, 512, flag);

    // x -> bf16
    convert_kernel<<<dim3(16384), 256, 0, stream>>>(
        (const float*)d_in[0], (const u16*)d_in[0], xbf, flag);

    // GEMM1: XCD-chunked 1D grid
    gemm1_kernel<<<dim3(4096), 256, 0, stream>>>(
        xbf, W1T, (const float*)d_in[2], (const u16*)d_in[2], proj, flag);

    // attention core: 1024 XCD-pinned wgs (16 qtiles x 64 batches), QBLK=64
    attn_kernel<<<dim3(1024), 512, 0, stream>>>(proj, obuf);

    // GEMM2: XCD-chunked 1D grid
    gemm2_kernel<<<dim3(2048), 256, 0, stream>>>(
        obuf, W2T, (const float*)d_in[4], (const u16*)d_in[4],
        (float*)d_out, (u16*)d_out, flag);
}

// Round 22
// 1095.026 us; speedup vs baseline: 1.0063x; 1.0063x over previous
//
#include <hip/hip_runtime.h>

typedef unsigned short u16;
typedef __attribute__((ext_vector_type(8))) short bf16x8;
typedef __attribute__((ext_vector_type(4))) float f32x4;

// ---- bf16 helpers (RNE) ----
__device__ inline float bf2f(u16 u) {
    unsigned v = ((unsigned)u) << 16;
    return __builtin_bit_cast(float, v);
}
__device__ inline u16 f2bf(float f) {
    unsigned u = __builtin_bit_cast(unsigned, f);
    u += 0x7fff + ((u >> 16) & 1);
    return (u16)(u >> 16);
}

// ---- async global->LDS 16B (wave-uniform LDS base + lane*16; per-lane gsrc)
__device__ inline void load_lds16(const u16* g, u16* l) {
    __builtin_amdgcn_global_load_lds(
        (const __attribute__((address_space(1))) unsigned int*)g,
        (__attribute__((address_space(3))) unsigned int*)l, 16, 0, 0);
}

// ============================================================
// Dtype detector (fp32 vs bf16 device buffers). flag=1 -> fp32.
// ============================================================
__global__ void detect_kernel(const u16* __restrict__ xr, int* __restrict__ flag) {
    __shared__ int red[4];
    const int t = threadIdx.x;
    int cnt = 0;
    for (int j = 0; j < 64; ++j) {
        u16 v = xr[(t * 64 + j) * 2];
        int e = (v >> 7) & 0xFF;
        cnt += (e >= 0x86);
    }
    for (int o = 32; o >= 1; o >>= 1) cnt += __shfl_xor(cnt, o);
    if ((t & 63) == 0) red[t >> 6] = cnt;
    __syncthreads();
    if (t == 0) flag[0] = ((red[0] + red[1] + red[2] + red[3]) > 1000) ? 1 : 0;
}

// ============================================================
// Convert x (fp32 or bf16) -> xbf (bf16), 8 elems/thread, one pass.
// ============================================================
__global__ __launch_bounds__(256) void convert_kernel(const float* __restrict__ xf,
                                                      const u16* __restrict__ xh,
                                                      u16* __restrict__ xbf,
                                                      const int* __restrict__ flag) {
    const bool isf32 = flag[0] != 0;
    size_t i = ((size_t)blockIdx.x * 256 + threadIdx.x) * 8;
    if (isf32) {
        f32x4 f0 = *(const f32x4*)&xf[i];
        f32x4 f1 = *(const f32x4*)&xf[i + 4];
        bf16x8 v;
#pragma unroll
        for (int j = 0; j < 4; ++j) {
            v[j] = (short)f2bf(f0[j]);
            v[j + 4] = (short)f2bf(f1[j]);
        }
        *(bf16x8*)&xbf[i] = v;
    } else {
        *(bf16x8*)&xbf[i] = *(const bf16x8*)&xh[i];
    }
}

// ============================================================
// Weight transpose + convert-to-bf16: dst[C][R] = bf16(src[R][C])
// ============================================================
__global__ __launch_bounds__(256) void transpose_kernel(const float* __restrict__ srcf,
                                                        const u16* __restrict__ srch,
                                                        u16* __restrict__ dst,
                                                        int R, int C,
                                                        const int* __restrict__ flag) {
    __shared__ u16 tile[64][65];
    const bool isf32 = flag[0] != 0;
    const int t = threadIdx.x;
    const int c0 = blockIdx.x * 64, r0 = blockIdx.y * 64;
    const int lc = t & 63, lr4 = t >> 6;
#pragma unroll
    for (int i = 0; i < 16; ++i) {
        int row = i * 4 + lr4;
        size_t idx = (size_t)(r0 + row) * C + c0 + lc;
        tile[row][lc] = isf32 ? f2bf(srcf[idx]) : srch[idx];
    }
    __syncthreads();
#pragma unroll
    for (int i = 0; i < 16; ++i) {
        int drow = i * 4 + lr4;
        dst[(size_t)(c0 + drow) * R + r0 + lc] = tile[lc][drow];
    }
}

// ============================================================
// GEMM1: proj[65536][1024] = xbf[65536][512] @ W1 + bias1, bf16 out
// global_load_lds width=16 staging + XCD-chunked 1D grid (r19/r20-proven).
// ============================================================
__global__ __launch_bounds__(256) void gemm1_kernel(const u16* __restrict__ xbf,
                                                    const u16* __restrict__ w1t,
                                                    const float* __restrict__ b1f,
                                                    const u16* __restrict__ b1h,
                                                    u16* __restrict__ proj,
                                                    const int* __restrict__ flag) {
    __shared__ u16 Al[128 * 64];
    __shared__ u16 Bl[128 * 64];
    const bool isf32 = flag[0] != 0;
    const int t = threadIdx.x;
    const int lane = t & 63;
    const int w = t >> 6;
    const int i_wg = blockIdx.x;
    const int xcd = i_wg & 7;
    const int j = i_wg >> 3;
    const int r0 = (xcd * 64 + (j >> 3)) * 128;
    const int c0 = (j & 7) * 128;
    const int wr = (w >> 1) * 64, wc = (w & 1) * 64;

    f32x4 acc[4][4] = {};

    for (int kt = 0; kt < 8; ++kt) {
        const int k0 = kt * 64;
#pragma unroll
        for (int i = 0; i < 4; ++i) {
            int c = i * 256 + t;
            int row = c >> 3;
            int off = (c & 7) * 8;
            load_lds16(&xbf[(size_t)(r0 + row) * 512 + k0 + off], &Al[row * 64 + off]);
            load_lds16(&w1t[(size_t)(c0 + row) * 512 + k0 + off], &Bl[row * 64 + off]);
        }
        __syncthreads();
#pragma unroll
        for (int kk = 0; kk < 64; kk += 32) {
            bf16x8 a[4], bb[4];
#pragma unroll
            for (int m = 0; m < 4; ++m)
                a[m] = *(const bf16x8*)&Al[(wr + m * 16 + (lane & 15)) * 64 + kk + (lane >> 4) * 8];
#pragma unroll
            for (int n = 0; n < 4; ++n)
                bb[n] = *(const bf16x8*)&Bl[(wc + n * 16 + (lane & 15)) * 64 + kk + (lane >> 4) * 8];
#pragma unroll
            for (int m = 0; m < 4; ++m)
#pragma unroll
                for (int n = 0; n < 4; ++n)
                    acc[m][n] = __builtin_amdgcn_mfma_f32_16x16x32_bf16(a[m], bb[n], acc[m][n], 0, 0, 0);
        }
        __syncthreads();
    }

#pragma unroll
    for (int n = 0; n < 4; ++n) {
        int col = c0 + wc + n * 16 + (lane & 15);
        float bv = isf32 ? b1f[col] : bf2f(b1h[col]);
#pragma unroll
        for (int m = 0; m < 4; ++m) {
            int rbase = r0 + wr + m * 16 + (lane >> 4) * 4;
#pragma unroll
            for (int i = 0; i < 4; ++i)
                proj[(size_t)(rbase + i) * 1024 + col] = f2bf(acc[m][n][i] + bv);
        }
    }
}

// ============================================================
// Attention core per wg = (batch b, 64 query rows)  -- QBLK=64.
// r14/r18/r19/r20 configuration: empirical optimum. FROZEN (setprio probe
// r21 was null, reverted).
// ============================================================
__global__ __launch_bounds__(512, 2) void attn_kernel(const u16* __restrict__ proj,
                                                      u16* __restrict__ obuf) {
    __shared__ u16 Pl[64 * 512];            // 65536 B exactly
    const int t = threadIdx.x;
    const int lane = t & 63;
    const int w = t >> 6;                   // 0..7
    const int i_wg = blockIdx.x;
    const int xcd = i_wg & 7;
    const int q = (i_wg >> 3) & 15;
    const int b = (i_wg >> 7) * 8 + xcd;
    const int n0 = q * 64;
    const u16* pb = proj + (size_t)b * 1024 * 1024;
    const int g = lane >> 4;
    const int lr = lane & 15;

    // ---- Phase 1: S = Q @ relu(K)^T / 32, full 64x1024 in regs (4rf x 8cf)
    f32x4 acc[4][8] = {};
    const int mw = w * 128;
    for (int kk = 0; kk < 1024; kk += 32) {
        const int e = kk + g * 8;
        bf16x8 a[4];
#pragma unroll
        for (int rf = 0; rf < 4; ++rf)
            a[rf] = *(const bf16x8*)&pb[(size_t)(n0 + rf * 16 + lr) * 1024 + e];
#pragma unroll
        for (int c2 = 0; c2 < 2; ++c2) {     // kf in 2 chunks of 4 (reg relief)
            bf16x8 kf[4];
#pragma unroll
            for (int cf = 0; cf < 4; ++cf) {
                bf16x8 v = *(const bf16x8*)&pb[(size_t)(mw + c2 * 64 + cf * 16 + lr) * 1024 + e];
                v &= ~(v >> 15);   // bf16 relu
                kf[cf] = v;
            }
#pragma unroll
            for (int rf = 0; rf < 4; ++rf)
#pragma unroll
                for (int cf = 0; cf < 4; ++cf)
                    acc[rf][c2 * 4 + cf] =
                        __builtin_amdgcn_mfma_f32_16x16x32_bf16(a[rf], kf[cf], acc[rf][c2 * 4 + cf], 0, 0, 0);
        }
    }
    {
        const float sc = 1.0f / 32.0f;
#pragma unroll
        for (int rf = 0; rf < 4; ++rf)
#pragma unroll
            for (int cf = 0; cf < 8; ++cf)
#pragma unroll
                for (int i = 0; i < 4; ++i) acc[rf][cf][i] *= sc;
    }

    // ---- Phase 2: softmax. Row ri = rf*16 + g*4 + i; wave holds 8 cf x 16 lr.
    float* redm = (float*)Pl;          // [64][8] f32 (2 KiB) overlay
    float* reds = (float*)Pl + 512;    // [64][8] f32 (2 KiB) overlay
    {
#pragma unroll
        for (int rf = 0; rf < 4; ++rf)
#pragma unroll
            for (int i = 0; i < 4; ++i) {
                float m = acc[rf][0][i];
#pragma unroll
                for (int cf = 1; cf < 8; ++cf) m = fmaxf(m, acc[rf][cf][i]);
                for (int o = 8; o >= 1; o >>= 1) m = fmaxf(m, __shfl_xor(m, o));
                if (lr == 0) redm[(rf * 16 + g * 4 + i) * 8 + w] = m;
            }
    }
    __syncthreads();
    {
#pragma unroll
        for (int rf = 0; rf < 4; ++rf)
#pragma unroll
            for (int i = 0; i < 4; ++i) {
                int ri = rf * 16 + g * 4 + i;
                float m = redm[ri * 8 + 0];
#pragma unroll
                for (int w2 = 1; w2 < 8; ++w2) m = fmaxf(m, redm[ri * 8 + w2]);
                float s = 0.f;
#pragma unroll
                for (int cf = 0; cf < 8; ++cf) {
                    acc[rf][cf][i] = __expf(acc[rf][cf][i] - m);
                    s += acc[rf][cf][i];
                }
                for (int o = 8; o >= 1; o >>= 1) s += __shfl_xor(s, o);
                if (lr == 0) reds[ri * 8 + w] = s;
            }
    }
    __syncthreads();
    {
#pragma unroll
        for (int rf = 0; rf < 4; ++rf)
#pragma unroll
            for (int i = 0; i < 4; ++i) {
                int ri = rf * 16 + g * 4 + i;
                float s = reds[ri * 8 + 0];
#pragma unroll
                for (int w2 = 1; w2 < 8; ++w2) s += reds[ri * 8 + w2];
                float inv = 1.0f / s;
#pragma unroll
                for (int cf = 0; cf < 8; ++cf) acc[rf][cf][i] *= inv;
            }
    }
    __syncthreads();   // reduce overlay consumed -> P may overwrite

    // ---- Phase 3: O = P @ V ; es = e-set (512 cols), h = key-half.
    const int ew = w * 64;
#pragma unroll
    for (int es = 0; es < 2; ++es) {
        f32x4 acc2[4][4] = {};
#pragma unroll
        for (int h = 0; h < 2; ++h) {
            // waves owning key-half h write P-half [64][512] from live acc
            if ((w >> 2) == h) {
                char* Pb = (char*)Pl;
                const int cb = (w & 3) * 128;   // local key-col base
#pragma unroll
                for (int rf = 0; rf < 4; ++rf)
#pragma unroll
                    for (int i = 0; i < 4; ++i) {
                        int ri = rf * 16 + g * 4 + i;
                        int rx = (ri & 7) << 4;
                        char* prow = Pb + ri * 1024;
#pragma unroll
                        for (int cf = 0; cf < 8; ++cf) {
                            int c = cb + cf * 16 + lr;
                            *(u16*)(prow + ((2 * c) ^ rx)) = f2bf(acc[rf][cf][i]);
                        }
                    }
            }
            __syncthreads();
            // PV over keys [512h, 512h+512), wave's 64 e-cols in e-set es
            const char* Pb = (const char*)Pl;
            for (int m0 = 0; m0 < 512; m0 += 32) {
                const int mq = m0 + g * 8;
                bf16x8 pa[4];
#pragma unroll
                for (int rf = 0; rf < 4; ++rf) {
                    int pr = rf * 16 + lr;
                    pa[rf] = *(const bf16x8*)(Pb + pr * 1024 + ((2 * mq) ^ ((pr & 7) << 4)));
                }
#pragma unroll
                for (int cf = 0; cf < 4; ++cf) {
                    const u16* vp = &pb[(size_t)(h * 512 + mq) * 1024 + es * 512 + ew + cf * 16 + lr];
                    bf16x8 vv;
#pragma unroll
                    for (int j = 0; j < 8; ++j) vv[j] = (short)vp[(size_t)j * 1024];
#pragma unroll
                    for (int rf = 0; rf < 4; ++rf)
                        acc2[rf][cf] = __builtin_amdgcn_mfma_f32_16x16x32_bf16(pa[rf], vv, acc2[rf][cf], 0, 0, 0);
                }
            }
            __syncthreads();   // PV done before next P-half overwrite
        }
        // obuf write for this e-set
#pragma unroll
        for (int rf = 0; rf < 4; ++rf)
#pragma unroll
            for (int cf = 0; cf < 4; ++cf)
#pragma unroll
                for (int i = 0; i < 4; ++i)
                    obuf[((size_t)b * 1024 + n0 + rf * 16 + g * 4 + i) * 1024 +
                         es * 512 + ew + cf * 16 + lr] = f2bf(acc2[rf][cf][i]);
    }
}

// ============================================================
// GEMM2: out[65536][512] = relu(O[65536][1024] @ W2 + bias2)
// global_load_lds staging + XCD-chunked 1D grid (r19/r20-proven).
// ============================================================
__global__ __launch_bounds__(256) void gemm2_kernel(const u16* __restrict__ obuf,
                                                    const u16* __restrict__ w2t,
                                                    const float* __restrict__ b2f,
                                                    const u16* __restrict__ b2h,
                                                    float* __restrict__ outf,
                                                    u16* __restrict__ outh,
                                                    const int* __restrict__ flag) {
    __shared__ u16 Al[128 * 64];
    __shared__ u16 Bl[128 * 64];
    const bool isf32 = flag[0] != 0;
    const int t = threadIdx.x;
    const int lane = t & 63;
    const int w = t >> 6;
    const int i_wg = blockIdx.x;
    const int xcd = i_wg & 7;
    const int j = i_wg >> 3;
    const int r0 = (xcd * 64 + (j >> 2)) * 128;
    const int c0 = (j & 3) * 128;
    const int wr = (w >> 1) * 64, wc = (w & 1) * 64;

    f32x4 acc[4][4] = {};

    for (int kt = 0; kt < 16; ++kt) {
        const int k0 = kt * 64;
#pragma unroll
        for (int i = 0; i < 4; ++i) {
            int c = i * 256 + t;
            int row = c >> 3;
            int off = (c & 7) * 8;
            load_lds16(&obuf[(size_t)(r0 + row) * 1024 + k0 + off], &Al[row * 64 + off]);
            load_lds16(&w2t[(size_t)(c0 + row) * 1024 + k0 + off], &Bl[row * 64 + off]);
        }
        __syncthreads();
#pragma unroll
        for (int kk = 0; kk < 64; kk += 32) {
            bf16x8 a[4], bb[4];
#pragma unroll
            for (int m = 0; m < 4; ++m)
                a[m] = *(const bf16x8*)&Al[(wr + m * 16 + (lane & 15)) * 64 + kk + (lane >> 4) * 8];
#pragma unroll
            for (int n = 0; n < 4; ++n)
                bb[n] = *(const bf16x8*)&Bl[(wc + n * 16 + (lane & 15)) * 64 + kk + (lane >> 4) * 8];
#pragma unroll
            for (int m = 0; m < 4; ++m)
#pragma unroll
                for (int n = 0; n < 4; ++n)
                    acc[m][n] = __builtin_amdgcn_mfma_f32_16x16x32_bf16(a[m], bb[n], acc[m][n], 0, 0, 0);
        }
        __syncthreads();
    }

#pragma unroll
    for (int n = 0; n < 4; ++n) {
        int col = c0 + wc + n * 16 + (lane & 15);
        float bv = isf32 ? b2f[col] : bf2f(b2h[col]);
#pragma unroll
        for (int m = 0; m < 4; ++m) {
            int rbase = r0 + wr + m * 16 + (lane >> 4) * 4;
#pragma unroll
            for (int i = 0; i < 4; ++i) {
                float v = fmaxf(acc[m][n][i] + bv, 0.f);
                size_t oi = (size_t)(rbase + i) * 512 + col;
                if (isf32) outf[oi] = v;
                else outh[oi] = f2bf(v);
            }
        }
    }
}

// ============================================================
// Launch. ws: [0,1MB) W1T | [1MB,2MB) W2T | [2MB,130MB) proj | flag @130MB
//         | obuf [65536][1024] bf16 @130MB+4KB
// xbf (64MB) ALIASES the start of obuf (dead before attn writes obuf).
// ============================================================
extern "C" void kernel_launch(void* const* d_in, const int* in_sizes, int n_in,
                              void* d_out, int out_size, void* d_ws, size_t ws_size,
                              hipStream_t stream) {
    char* ws = (char*)d_ws;
    u16* W1T  = (u16*)ws;
    u16* W2T  = (u16*)(ws + (1u << 20));
    u16* proj = (u16*)(ws + (2u << 20));
    int* flag = (int*)(ws + ((size_t)130 << 20));
    u16* obuf = (u16*)(ws + ((size_t)130 << 20) + 4096);
    u16* xbf  = obuf;   // alias: dead before attn writes obuf

    detect_kernel<<<1, 256, 0, stream>>>((const u16*)d_in[0], flag);

    transpose_kernel<<<dim3(16, 8, 1), 256, 0, stream>>>(
        (const float*)d_in[1], (const u16*)d_in[1], W1T, 512, 1024, flag);
    transpose_kernel<<<dim3(8, 16, 1), 256, 0, stream>>>(
        (const float*)d_in[3], (const u16*)d_in[3], W2T, 1024, 512, flag);

    // x -> bf16
    convert_kernel<<<dim3(16384), 256, 0, stream>>>(
        (const float*)d_in[0], (const u16*)d_in[0], xbf, flag);

    // GEMM1: XCD-chunked 1D grid
    gemm1_kernel<<<dim3(4096), 256, 0, stream>>>(
        xbf, W1T, (const float*)d_in[2], (const u16*)d_in[2], proj, flag);

    // attention core: 1024 XCD-pinned wgs (16 qtiles x 64 batches), QBLK=64
    attn_kernel<<<dim3(1024), 512, 0, stream>>>(proj, obuf);

    // GEMM2: XCD-chunked 1D grid
    gemm2_kernel<<<dim3(2048), 256, 0, stream>>>(
        obuf, W2T, (const float*)d_in[4], (const u16*)d_in[4],
        (float*)d_out, (u16*)d_out, flag);
}